// Round 8
// baseline (1609.865 us; speedup 1.0000x reference)
//
#include <hip/hip_runtime.h>
#include <math.h>

#define BB 4
#define TT 8
#define CC 128
#define HWW 9216            // 96*96
#define NPG 1179648.0f      // C*H*W per (b,t) group
#define EPS 1e-5f
#define SCALE 0.17677669529663687f    // 1/sqrt(32)
#define SCALE2 0.2550181765195206f    // SCALE * log2(e)

// ws layout in floats: part[4096*2] | A[32][128] | B[32][128]
#define WS_PART 0
#define WS_A    8192
#define WS_B    12288

typedef __attribute__((ext_vector_type(4))) float f32x4;

// stats: one block per (g, c) row; non-atomic per-block partial stores (R6-proven).
__global__ __launch_bounds__(256) void stats_kernel(
    const float* __restrict__ x, const float* __restrict__ pe,
    float* __restrict__ part)
{
    const int bid = blockIdx.x;              // 4096 = 32 g x 128 c
    const int g = bid >> 7, c = bid & 127;
    const int t = g & 7;
    const int tid = threadIdx.x;
    const float pec = pe[t * CC + c];
    const float4* row = (const float4*)(x + ((size_t)g * CC + c) * HWW);
    float s1 = 0.f, s2 = 0.f;
    #pragma unroll
    for (int i = 0; i < 9; ++i) {            // 9*256 = 2304 float4 = 9216 floats
        float4 v = row[tid + i * 256];
        float a = v.x + pec, b = v.y + pec, cc2 = v.z + pec, d = v.w + pec;
        s1 += (a + b) + (cc2 + d);
        s2 += (a * a + b * b) + (cc2 * cc2 + d * d);
    }
    for (int off = 32; off; off >>= 1) {
        s1 += __shfl_down(s1, off);
        s2 += __shfl_down(s2, off);
    }
    __shared__ float red[8];
    const int wid = tid >> 6, lane = tid & 63;
    if (lane == 0) { red[wid] = s1; red[4 + wid] = s2; }
    __syncthreads();
    if (tid == 0) {
        part[bid * 2 + 0] = red[0] + red[1] + red[2] + red[3];
        part[bid * 2 + 1] = red[4] + red[5] + red[6] + red[7];
    }
}

// finalize: block g reduces its 128 c-partials (R6-proven).
__global__ __launch_bounds__(128) void finalize_kernel(
    const float* __restrict__ pe, const float* __restrict__ nw,
    const float* __restrict__ nb, float* ws)
{
    const int g = blockIdx.x;
    const int c = threadIdx.x;               // 0..127
    const float* part = ws + WS_PART + g * 256;
    float s1 = part[c * 2 + 0];
    float s2 = part[c * 2 + 1];
    for (int off = 32; off; off >>= 1) {
        s1 += __shfl_down(s1, off);
        s2 += __shfl_down(s2, off);
    }
    __shared__ float r[4];
    const int wid = c >> 6, lane = c & 63;
    if (lane == 0) { r[wid] = s1; r[2 + wid] = s2; }
    __syncthreads();
    const float inv = 1.0f / NPG;
    const float mean = (r[0] + r[1]) * inv;
    const float var  = (r[2] + r[3]) * inv - mean * mean;
    const float rstd = rsqrtf(var + EPS);
    const int t = g & 7;
    const float a = rstd * nw[c];
    ws[WS_A + g * CC + c] = a;
    ws[WS_B + g * CC + c] = (pe[t * CC + c] - mean) * a + nb[c];
}

// fused8 = fused7 phase skeleton with TRANSPOSED+SWIZZLED LDS tiles.
// Tile layout: [pos][channel], dword addr = pos*128 + ((chunk ^ ((pos>>3)&7))<<2)
// + (c&3), chunk = c>>2. Channel walks become ds_read_b128 (4x fewer LDS read
// instrs: score 32->8, q7 128->32, xb 32->8, y 256->64; exchanges transposed
// too). Swizzle applied identically on write and read (both-sides rule).
// R7 PMC showed compute phases LDS-read-throughput-bound (VALUBusy 29%).
// 1024 threads = 16 waves, wave = (head n = w>>2, quarter hq = w&3), lane = pos.
__global__ __launch_bounds__(1024, 8) void fused8_kernel(
    const float* __restrict__ x, const float* __restrict__ ws,
    const float* __restrict__ qkv_w, const float* __restrict__ proj_w,
    float* __restrict__ out)
{
    __shared__ __align__(16) float bufA[64 * CC];
    __shared__ __align__(16) float bufB[64 * CC];

    const int tid  = threadIdx.x;
    const int lane = tid & 63;                  // position
    const int w    = tid >> 6;                  // wave 0..15
    const int wu   = __builtin_amdgcn_readfirstlane(w);
    const int n    = wu >> 2;                   // head
    const int hq   = wu & 3;                    // c-quarter
    const int b    = blockIdx.y;
    const int hw0  = blockIdx.x * 64;

    const int pg   = (lane >> 3) & 7;           // swizzle group for pos=lane
    const int rowb = lane * 128;                // dword row base for pos=lane

    // staging role: channel r, positions [k8, k8+8)
    const int r  = tid >> 3;                    // 0..127
    const int k8 = (tid & 7) * 8;               // 0,8,..,56

    const float* xrow = x + ((size_t)(b * TT) * CC + r) * HWW + hw0 + k8;
    const float* Arow = ws + WS_A + (b * TT) * CC + r;
    const float* Brow = ws + WS_B + (b * TT) * CC + r;

    f32x4 rg0, rg1;                             // tile fragment in flight
    float sa, sb;                               // its fold constants
    auto ldtile = [&](int t) {
        const float* p = xrow + (size_t)t * CC * HWW;
        rg0 = *(const f32x4*)(p);
        rg1 = *(const f32x4*)(p + 4);
        sa = Arow[t * CC];
        sb = Brow[t * CC];
    };
    // fold + 8 scalar ds_writes, transposed+swizzled. (k8+i)>>3 == k8>>3 for i<8.
    auto wrtile = [&](float* dst) {
        const int base = k8 * 128 + ((((r >> 2) ^ ((k8 >> 3) & 7)) << 2) | (r & 3));
        dst[base + 0 * 128] = fmaf(rg0.x, sa, sb);
        dst[base + 1 * 128] = fmaf(rg0.y, sa, sb);
        dst[base + 2 * 128] = fmaf(rg0.z, sa, sb);
        dst[base + 3 * 128] = fmaf(rg0.w, sa, sb);
        dst[base + 4 * 128] = fmaf(rg1.x, sa, sb);
        dst[base + 5 * 128] = fmaf(rg1.y, sa, sb);
        dst[base + 6 * 128] = fmaf(rg1.z, sa, sb);
        dst[base + 7 * 128] = fmaf(rg1.w, sa, sb);
    };

    float u[32];
    // score: 8 x ds_read_b128 over the wave's quarter channels
    auto score = [&](const float* buf) {
        float s0 = 0.f, s1 = 0.f, s2 = 0.f, s3 = 0.f;
        #pragma unroll
        for (int jj = 0; jj < 8; ++jj) {
            f32x4 v = *(const f32x4*)&buf[rowb + (((hq * 8 + jj) ^ pg) << 2)];
            s0 = fmaf(u[jj * 4 + 0], v.x, s0);
            s1 = fmaf(u[jj * 4 + 1], v.y, s1);
            s2 = fmaf(u[jj * 4 + 2], v.z, s2);
            s3 = fmaf(u[jj * 4 + 3], v.w, s3);
        }
        return (s0 + s1) + (s2 + s3);
    };

    // ---- prologue: tile 7 folded into bufA (transposed) ----
    ldtile(7);
    wrtile(bufA);
    __syncthreads();                            // tile7 ready

    // ---- q7 = Wq_n xn7 (8 d-rows per wave): 32 b128 reads -> bufB transposed ----
    {
        const float* Wq = qkv_w + (n * 32 + hq * 8) * CC;
        float q7[8] = {0.f,0.f,0.f,0.f,0.f,0.f,0.f,0.f};
        #pragma unroll
        for (int cc = 0; cc < 32; ++cc) {
            f32x4 xv = *(const f32x4*)&bufA[rowb + ((cc ^ pg) << 2)];
            #pragma unroll
            for (int d = 0; d < 8; ++d) {
                const float* Wr = Wq + d * CC + cc * 4;
                q7[d] = fmaf(Wr[0], xv.x, q7[d]);
                q7[d] = fmaf(Wr[1], xv.y, q7[d]);
                q7[d] = fmaf(Wr[2], xv.z, q7[d]);
                q7[d] = fmaf(Wr[3], xv.w, q7[d]);
            }
        }
        // transposed exchange: cols n*32+hq*8+d -> chunks n*8+hq*2, +1
        const int c0 = n * 8 + hq * 2;
        f32x4 e0, e1;
        e0.x = q7[0]; e0.y = q7[1]; e0.z = q7[2]; e0.w = q7[3];
        e1.x = q7[4]; e1.y = q7[5]; e1.z = q7[6]; e1.w = q7[7];
        *(f32x4*)&bufB[rowb + ((c0 ^ pg) << 2)]       = e0;
        *(f32x4*)&bufB[rowb + (((c0 + 1) ^ pg) << 2)] = e1;
    }
    __syncthreads();                            // q7 visible

    ldtile(0);                                  // t0 flies under u-compute

    // ---- u[32] = (Wk_n^T q7) slice hq*32..: 8 b128 reads ----
    #pragma unroll
    for (int j = 0; j < 32; ++j) u[j] = 0.f;
    {
        const float* Wk = qkv_w + (CC + n * 32) * CC + hq * 32;
        #pragma unroll
        for (int qq = 0; qq < 8; ++qq) {
            f32x4 qv = *(const f32x4*)&bufB[rowb + (((n * 8 + qq) ^ pg) << 2)];
            const float* W0 = Wk + (qq * 4 + 0) * CC;
            const float* W1 = Wk + (qq * 4 + 1) * CC;
            const float* W2 = Wk + (qq * 4 + 2) * CC;
            const float* W3 = Wk + (qq * 4 + 3) * CC;
            #pragma unroll
            for (int j = 0; j < 32; ++j) {
                u[j] = fmaf(W0[j], qv.x, u[j]);
                u[j] = fmaf(W1[j], qv.y, u[j]);
                u[j] = fmaf(W2[j], qv.z, u[j]);
                u[j] = fmaf(W3[j], qv.w, u[j]);
            }
        }
    }
    __syncthreads();                            // q7 reads done; bufB free

    // ---- phase A: 8 quarter-scores into regs, 1 barrier/tile ----
    float ps[8];
    wrtile(bufB);                               // t0 -> bufB
    ps[7] = score(bufA);
    ldtile(1);
    __syncthreads();                            // t0 visible; bufA (t7) dead

    #pragma unroll
    for (int t = 0; t < 7; ++t) {
        const float* curb = (t & 1) ? bufA : bufB;
        float* othb = (t & 1) ? bufB : bufA;
        if (t < 6) wrtile(othb);                // tile t+1 (from prev ldtile)
        if (t < 5) ldtile(t + 2);
        ps[t] = score(curb);
        __syncthreads();
    }

    // ---- transposed ps exchange into bufA + exact softmax ----
    ldtile(0);                                  // phase-B t0 prefetch
    {
        const int p0 = wu * 2;                  // cols wu*8+t -> chunks wu*2, +1
        f32x4 e0, e1;
        e0.x = ps[0]; e0.y = ps[1]; e0.z = ps[2]; e0.w = ps[3];
        e1.x = ps[4]; e1.y = ps[5]; e1.z = ps[6]; e1.w = ps[7];
        *(f32x4*)&bufA[rowb + ((p0 ^ pg) << 2)]       = e0;
        *(f32x4*)&bufA[rowb + (((p0 + 1) ^ pg) << 2)] = e1;
    }
    __syncthreads();

    float wt[8];
    {
        float wq[32];
        #pragma unroll
        for (int qq = 0; qq < 8; ++qq) {
            f32x4 v = *(const f32x4*)&bufA[rowb + (((n * 8 + qq) ^ pg) << 2)];
            wq[qq * 4 + 0] = v.x; wq[qq * 4 + 1] = v.y;
            wq[qq * 4 + 2] = v.z; wq[qq * 4 + 3] = v.w;
        }
        float sreg[8];
        #pragma unroll
        for (int t = 0; t < 8; ++t)
            sreg[t] = (wq[t] + wq[8 + t]) + (wq[16 + t] + wq[24 + t]);
        float m = fmaxf(fmaxf(fmaxf(sreg[0], sreg[1]), fmaxf(sreg[2], sreg[3])),
                        fmaxf(fmaxf(sreg[4], sreg[5]), fmaxf(sreg[6], sreg[7])));
        float l = 0.f;
        #pragma unroll
        for (int t = 0; t < 8; ++t) { wt[t] = exp2f((sreg[t] - m) * SCALE2); l += wt[t]; }
        const float invl = 1.0f / l;
        #pragma unroll
        for (int t = 0; t < 8; ++t) wt[t] *= invl;
    }
    __syncthreads();                            // exchange reads done; bufA free

    // ---- phase B: restage 8 tiles (L2-hot), xb += wt * xnf (8 b128/tile) ----
    float xb[32];
    #pragma unroll
    for (int j = 0; j < 32; ++j) xb[j] = 0.f;
    #pragma unroll
    for (int t = 0; t < 8; ++t) {
        float* wb = (t & 1) ? bufB : bufA;
        wrtile(wb);                             // tile t (from prev ldtile)
        if (t < 7) ldtile(t + 1);
        if (t >= 1) {
            const float* rb = (t & 1) ? bufA : bufB;   // wb(t-1)
            const float wc = wt[t - 1];
            #pragma unroll
            for (int jj = 0; jj < 8; ++jj) {
                f32x4 v = *(const f32x4*)&rb[rowb + (((hq * 8 + jj) ^ pg) << 2)];
                xb[jj * 4 + 0] = fmaf(v.x, wc, xb[jj * 4 + 0]);
                xb[jj * 4 + 1] = fmaf(v.y, wc, xb[jj * 4 + 1]);
                xb[jj * 4 + 2] = fmaf(v.z, wc, xb[jj * 4 + 2]);
                xb[jj * 4 + 3] = fmaf(v.w, wc, xb[jj * 4 + 3]);
            }
        }
        __syncthreads();
    }
    {                                           // tail: consume t7 from bufB
        const float wc = wt[7];
        #pragma unroll
        for (int jj = 0; jj < 8; ++jj) {
            f32x4 v = *(const f32x4*)&bufB[rowb + (((hq * 8 + jj) ^ pg) << 2)];
            xb[jj * 4 + 0] = fmaf(v.x, wc, xb[jj * 4 + 0]);
            xb[jj * 4 + 1] = fmaf(v.y, wc, xb[jj * 4 + 1]);
            xb[jj * 4 + 2] = fmaf(v.z, wc, xb[jj * 4 + 2]);
            xb[jj * 4 + 3] = fmaf(v.w, wc, xb[jj * 4 + 3]);
        }
    }
    __syncthreads();                            // all tile reads done; bufs free

    // ---- v: quarter partials, transposed b128 writes; pairwise tree merge ----
    // v01 (hq0+hq1) -> bufB; v23 (hq2+hq3) -> bufA. Same swizzle.
    {
        const float* Wv = qkv_w + (2 * CC + n * 32) * CC + hq * 32;
        float vprev[8];
        #pragma unroll
        for (int gi = 0; gi < 4; ++gi) {
            float vp[8];
            #pragma unroll
            for (int d = 0; d < 8; ++d) {
                float s0 = 0.f, s1 = 0.f, s2 = 0.f, s3 = 0.f;
                const float* Wr = Wv + (gi * 8 + d) * CC;
                #pragma unroll
                for (int c = 0; c < 32; c += 4) {
                    s0 = fmaf(Wr[c + 0], xb[c + 0], s0);
                    s1 = fmaf(Wr[c + 1], xb[c + 1], s1);
                    s2 = fmaf(Wr[c + 2], xb[c + 2], s2);
                    s3 = fmaf(Wr[c + 3], xb[c + 3], s3);
                }
                vp[d] = (s0 + s1) + (s2 + s3);
            }
            const int q0 = n * 8 + gi * 2;      // chunks for cols n*32+gi*8..+7
            if (hq == 1 || hq == 3) {
                float* dst = (hq == 1) ? bufB : bufA;
                f32x4 w0, w1;
                w0.x = vp[0]; w0.y = vp[1]; w0.z = vp[2]; w0.w = vp[3];
                w1.x = vp[4]; w1.y = vp[5]; w1.z = vp[6]; w1.w = vp[7];
                *(f32x4*)&dst[rowb + ((q0 ^ pg) << 2)]       = w0;
                *(f32x4*)&dst[rowb + (((q0 + 1) ^ pg) << 2)] = w1;
            }
            if (gi > 0 && (hq == 0 || hq == 2)) {      // merge group gi-1
                float* dst = (hq == 0) ? bufB : bufA;
                const int m0 = n * 8 + (gi - 1) * 2;
                f32x4 c0 = *(const f32x4*)&dst[rowb + ((m0 ^ pg) << 2)];
                f32x4 c1 = *(const f32x4*)&dst[rowb + (((m0 + 1) ^ pg) << 2)];
                c0.x += vprev[0]; c0.y += vprev[1]; c0.z += vprev[2]; c0.w += vprev[3];
                c1.x += vprev[4]; c1.y += vprev[5]; c1.z += vprev[6]; c1.w += vprev[7];
                *(f32x4*)&dst[rowb + ((m0 ^ pg) << 2)]       = c0;
                *(f32x4*)&dst[rowb + (((m0 + 1) ^ pg) << 2)] = c1;
            }
            #pragma unroll
            for (int d = 0; d < 8; ++d) vprev[d] = vp[d];
            __syncthreads();
        }
        if (hq == 0 || hq == 2) {               // final merge (group 3)
            float* dst = (hq == 0) ? bufB : bufA;
            const int m0 = n * 8 + 6;
            f32x4 c0 = *(const f32x4*)&dst[rowb + ((m0 ^ pg) << 2)];
            f32x4 c1 = *(const f32x4*)&dst[rowb + (((m0 + 1) ^ pg) << 2)];
            c0.x += vprev[0]; c0.y += vprev[1]; c0.z += vprev[2]; c0.w += vprev[3];
            c1.x += vprev[4]; c1.y += vprev[5]; c1.z += vprev[6]; c1.w += vprev[7];
            *(f32x4*)&dst[rowb + ((m0 ^ pg) << 2)]       = c0;
            *(f32x4*)&dst[rowb + (((m0 + 1) ^ pg) << 2)] = c1;
        }
    }
    __syncthreads();                            // v01/v23 complete

    // ---- y[e] = sum_c P[e][c]*(v01[c]+v23[c]): 64 b128 reads total ----
    float y[8];
    #pragma unroll
    for (int e = 0; e < 8; ++e) y[e] = 0.f;
    #pragma unroll
    for (int cc = 0; cc < 32; ++cc) {
        f32x4 va = *(const f32x4*)&bufB[rowb + ((cc ^ pg) << 2)];
        f32x4 vb = *(const f32x4*)&bufA[rowb + ((cc ^ pg) << 2)];
        const float v0 = va.x + vb.x, v1 = va.y + vb.y;
        const float v2 = va.z + vb.z, v3 = va.w + vb.w;
        #pragma unroll
        for (int e = 0; e < 8; ++e) {
            const float* Pr = proj_w + (wu * 8 + e) * CC + cc * 4;  // SGPR base
            y[e] = fmaf(Pr[0], v0, y[e]);
            y[e] = fmaf(Pr[1], v1, y[e]);
            y[e] = fmaf(Pr[2], v2, y[e]);
            y[e] = fmaf(Pr[3], v3, y[e]);
        }
    }
    const size_t ob = (size_t)(b * CC + wu * 8) * HWW + hw0 + lane;
    #pragma unroll
    for (int e = 0; e < 8; ++e)
        out[ob + (size_t)e * HWW] = y[e];
}

extern "C" void kernel_launch(void* const* d_in, const int* in_sizes, int n_in,
                              void* d_out, int out_size, void* d_ws, size_t ws_size,
                              hipStream_t stream) {
    const float* x      = (const float*)d_in[0];
    const float* pe     = (const float*)d_in[1];
    const float* nw     = (const float*)d_in[2];
    const float* nb     = (const float*)d_in[3];
    const float* qkv_w  = (const float*)d_in[4];
    const float* proj_w = (const float*)d_in[5];
    float* out = (float*)d_out;
    float* ws  = (float*)d_ws;

    stats_kernel<<<4096, 256, 0, stream>>>(x, pe, ws + WS_PART);
    finalize_kernel<<<32, 128, 0, stream>>>(pe, nw, nb, ws);
    fused8_kernel<<<dim3(HWW / 64, BB), 1024, 0, stream>>>(x, ws, qkv_w, proj_w, out);
}